// Round 1
// baseline (793.283 us; speedup 1.0000x reference)
//
#include <hip/hip_runtime.h>
#include <hip/hip_bf16.h>
#include <math.h>

typedef __attribute__((ext_vector_type(8))) short short8;
typedef __attribute__((ext_vector_type(4))) float f32x4;

#define C_IN 128
#define OC_ 128
#define BB 8
#define KBANK 4

__device__ __forceinline__ unsigned short f2bf(float f) {
  union { float f; unsigned int u; } v; v.f = f;
  unsigned int u = v.u;
  unsigned int r = u + 0x7fffu + ((u >> 16) & 1u);
  return (unsigned short)(r >> 16);
}

// ---------------- Kernel 1: per-(b,c) global mean ----------------
__global__ void k_pool(const float* __restrict__ x, float* __restrict__ pooled) {
  int plane = blockIdx.x;  // 0..1023 = b*128+c
  const float4* p = (const float4*)(x + (size_t)plane * 65536);
  float s = 0.f;
  for (int i = threadIdx.x; i < 16384; i += 256) {
    float4 v = p[i];
    s += (v.x + v.y) + (v.z + v.w);
  }
  #pragma unroll
  for (int off = 32; off > 0; off >>= 1) s += __shfl_down(s, off);
  __shared__ float red[4];
  if ((threadIdx.x & 63) == 0) red[threadIdx.x >> 6] = s;
  __syncthreads();
  if (threadIdx.x == 0)
    pooled[plane] = (red[0] + red[1] + red[2] + red[3]) * (1.0f / 65536.0f);
}

// ---------------- Kernel 2: attention softmax + dynamic kernel + bf16 pw ----
__global__ void k_prep(const float* __restrict__ pooled,
                       const float* __restrict__ attn_w,
                       const float* __restrict__ attn_b,
                       const float* __restrict__ bank,   // [4][128][1][3][3]
                       const float* __restrict__ pw_w,   // [128][128]
                       float* __restrict__ dynk,         // out: [8][128][9]
                       unsigned short* __restrict__ pwb) // out: [128][128] bf16
{
  __shared__ float attn_s[BB][KBANK];
  int tid = threadIdx.x;
  if (tid < BB * KBANK) {
    int b = tid >> 2, k = tid & 3;
    float s = attn_b[k];
    for (int c = 0; c < C_IN; ++c) s += pooled[b * C_IN + c] * attn_w[k * C_IN + c];
    attn_s[b][k] = s;
  }
  __syncthreads();
  if (tid < BB) {
    int b = tid;
    float l0 = attn_s[b][0], l1 = attn_s[b][1], l2 = attn_s[b][2], l3 = attn_s[b][3];
    float m = fmaxf(fmaxf(l0, l1), fmaxf(l2, l3));
    float e0 = expf(l0 - m), e1 = expf(l1 - m), e2 = expf(l2 - m), e3 = expf(l3 - m);
    float inv = 1.0f / (e0 + e1 + e2 + e3);
    attn_s[b][0] = e0 * inv; attn_s[b][1] = e1 * inv;
    attn_s[b][2] = e2 * inv; attn_s[b][3] = e3 * inv;
  }
  __syncthreads();
  for (int i = tid; i < BB * C_IN * 9; i += 256) {
    int b = i / (C_IN * 9);
    int rem = i - b * (C_IN * 9);   // c*9 + ij
    float v = 0.f;
    #pragma unroll
    for (int k = 0; k < KBANK; ++k) v += attn_s[b][k] * bank[k * (C_IN * 9) + rem];
    dynk[i] = v;
  }
  for (int i = tid; i < OC_ * C_IN; i += 256) pwb[i] = f2bf(pw_w[i]);
}

// ---------------- Kernel 3: fused depthwise 3x3 + pointwise MFMA ----------
// Block: 256 threads (4 waves). Tile: b fixed, 8 rows x 16 cols = 128 pixels.
// GEMM per block: D[o=128][p=128] = sum_c pw[o][c] * dw[c][p], K chunked by 32.
// Wave w computes o in [32w, 32w+32): 2 m-tiles x 8 n-tiles of 16x16x32 MFMA.
__global__ __launch_bounds__(256, 2) void k_main(
    const float* __restrict__ x,
    const float* __restrict__ dynk,
    const unsigned short* __restrict__ pwb,
    const float* __restrict__ pw_b,
    float* __restrict__ out) {
  constexpr int RS = 20;          // xs row stride (floats): 16B-aligned rows
  constexpr int PS = 10 * RS;     // per-channel plane: 10 rows
  __shared__ float xs[32 * PS];            // 25600 B
  __shared__ unsigned short dws[128 * 40]; // [pixel][k_local padded] 10240 B

  const int b  = blockIdx.z;
  const int h0 = blockIdx.y * 8;
  const int w0 = blockIdx.x * 16;
  const int tid  = threadIdx.x;
  const int wv   = tid >> 6;
  const int lane = tid & 63;
  const int quad = lane >> 4;
  const int l15  = lane & 15;
  const int cl   = tid & 31;  // producer: chunk-local channel
  const int prow = tid >> 5;  // producer: pixel row 0..7

  // A fragments (pw, bf16) held in registers for the whole block.
  // A[m][k]: m = l15 (o within 16-tile), k = quad*8 + j.
  short8 afrag[2][4];
  #pragma unroll
  for (int mt = 0; mt < 2; ++mt) {
    #pragma unroll
    for (int kc = 0; kc < 4; ++kc) {
      int o = wv * 32 + mt * 16 + l15;
      afrag[mt][kc] = *(const short8*)(pwb + ((size_t)o * C_IN + kc * 32 + quad * 8));
    }
  }

  f32x4 acc[2][8];
  #pragma unroll
  for (int mt = 0; mt < 2; ++mt)
    #pragma unroll
    for (int nt = 0; nt < 8; ++nt)
      acc[mt][nt] = (f32x4){0.f, 0.f, 0.f, 0.f};

  #pragma unroll
  for (int kc = 0; kc < 4; ++kc) {
    __syncthreads();  // previous chunk's MFMA reads done before overwrite
    const int cbase = kc * 32;
    // ---- stage x halo tile: 32 ch x 10 rows x 18 cols, zero-padded ----
    for (int i = tid; i < 5760; i += 256) {
      int c = i / 180;
      int rem = i - c * 180;
      int r = rem / 18;
      int col = rem - r * 18;
      int gh = h0 - 1 + r, gw = w0 - 1 + col;
      float v = 0.f;
      if ((unsigned)gh < 256u && (unsigned)gw < 256u)
        v = x[(((size_t)(b * C_IN + cbase + c)) << 16) + (gh << 8) + gw];
      xs[c * PS + r * RS + col] = v;
    }
    __syncthreads();
    // ---- depthwise: thread = (channel cl, pixel row prow), 16 cols ----
    float k9[9];
    {
      const float* kp = dynk + (size_t)(b * C_IN + cbase + cl) * 9;
      #pragma unroll
      for (int t = 0; t < 9; ++t) k9[t] = kp[t];
    }
    float accd[16];
    #pragma unroll
    for (int col = 0; col < 16; ++col) accd[col] = 0.f;
    const float* xp = &xs[cl * PS + prow * RS];
    #pragma unroll
    for (int i = 0; i < 3; ++i) {
      float xr[18];
      const float* rp = xp + i * RS;
      #pragma unroll
      for (int j = 0; j < 9; ++j) {
        float2 t = *(const float2*)(rp + 2 * j);
        xr[2 * j] = t.x; xr[2 * j + 1] = t.y;
      }
      float c0 = k9[3 * i], c1 = k9[3 * i + 1], c2 = k9[3 * i + 2];
      #pragma unroll
      for (int col = 0; col < 16; ++col)
        accd[col] = fmaf(c0, xr[col], fmaf(c1, xr[col + 1], fmaf(c2, xr[col + 2], accd[col])));
    }
    // dw -> LDS in MFMA-B layout: B[k=cl][n=pixel], stored [pixel][k] padded
    #pragma unroll
    for (int col = 0; col < 16; ++col)
      dws[(prow * 16 + col) * 40 + cl] = f2bf(accd[col]);
    __syncthreads();
    // ---- MFMA: 16 per wave per chunk ----
    #pragma unroll
    for (int nt = 0; nt < 8; ++nt) {
      short8 bfrag = *(const short8*)&dws[(nt * 16 + l15) * 40 + quad * 8];
      acc[0][nt] = __builtin_amdgcn_mfma_f32_16x16x32_bf16(afrag[0][kc], bfrag, acc[0][nt], 0, 0, 0);
      acc[1][nt] = __builtin_amdgcn_mfma_f32_16x16x32_bf16(afrag[1][kc], bfrag, acc[1][nt], 0, 0, 0);
    }
  }
  // ---- epilogue: D[row=o][col=pixel]; pixel = nt*16 + l15 -> (h0+nt, w0+l15)
  #pragma unroll
  for (int mt = 0; mt < 2; ++mt) {
    #pragma unroll
    for (int r = 0; r < 4; ++r) {
      int o = wv * 32 + mt * 16 + quad * 4 + r;
      float bias = pw_b[o];
      size_t obase = ((size_t)(b * OC_ + o)) << 16;
      #pragma unroll
      for (int nt = 0; nt < 8; ++nt)
        out[obase + ((h0 + nt) << 8) + (w0 + l15)] = acc[mt][nt][r] + bias;
    }
  }
}

extern "C" void kernel_launch(void* const* d_in, const int* in_sizes, int n_in,
                              void* d_out, int out_size, void* d_ws, size_t ws_size,
                              hipStream_t stream) {
  const float* x      = (const float*)d_in[0];
  const float* bank   = (const float*)d_in[1];
  const float* attn_w = (const float*)d_in[2];
  const float* attn_b = (const float*)d_in[3];
  const float* pw_w   = (const float*)d_in[4];
  const float* pw_b   = (const float*)d_in[5];
  float* out = (float*)d_out;

  char* ws = (char*)d_ws;
  float* pooled       = (float*)ws;                       // 1024 f32
  float* dynk         = (float*)(ws + 4096);              // 9216 f32
  unsigned short* pwb = (unsigned short*)(ws + 4096 + 36864); // 16384 bf16

  k_pool<<<1024, 256, 0, stream>>>(x, pooled);
  k_prep<<<1, 256, 0, stream>>>(pooled, attn_w, attn_b, bank, pw_w, dynk, pwb);
  dim3 grid(16, 32, 8);  // (W/16, H/8, B)
  k_main<<<grid, 256, 0, stream>>>(x, dynk, pwb, pw_b, out);
}

// Round 2
// 637.844 us; speedup vs baseline: 1.2437x; 1.2437x over previous
//
#include <hip/hip_runtime.h>
#include <hip/hip_bf16.h>
#include <math.h>

typedef __attribute__((ext_vector_type(8))) short short8;
typedef __attribute__((ext_vector_type(4))) float f32x4;

#define C_IN 128
#define OC_ 128
#define BB 8
#define KBANK 4

__device__ __forceinline__ unsigned short f2bf(float f) {
  union { float f; unsigned int u; } v; v.f = f;
  unsigned int u = v.u;
  unsigned int r = u + 0x7fffu + ((u >> 16) & 1u);
  return (unsigned short)(r >> 16);
}

// ---------------- Kernel 1: per-(b,c) global mean ----------------
__global__ void k_pool(const float* __restrict__ x, float* __restrict__ pooled) {
  int plane = blockIdx.x;  // 0..1023 = b*128+c
  const float4* p = (const float4*)(x + (size_t)plane * 65536);
  float s0 = 0.f, s1 = 0.f, s2 = 0.f, s3 = 0.f;
  for (int i = threadIdx.x; i < 16384; i += 1024) {
    float4 a = p[i];
    float4 b = p[i + 256];
    float4 c = p[i + 512];
    float4 d = p[i + 768];
    s0 += (a.x + a.y) + (a.z + a.w);
    s1 += (b.x + b.y) + (b.z + b.w);
    s2 += (c.x + c.y) + (c.z + c.w);
    s3 += (d.x + d.y) + (d.z + d.w);
  }
  float s = (s0 + s1) + (s2 + s3);
  #pragma unroll
  for (int off = 32; off > 0; off >>= 1) s += __shfl_down(s, off);
  __shared__ float red[4];
  if ((threadIdx.x & 63) == 0) red[threadIdx.x >> 6] = s;
  __syncthreads();
  if (threadIdx.x == 0)
    pooled[plane] = (red[0] + red[1] + red[2] + red[3]) * (1.0f / 65536.0f);
}

// ---------------- Kernel 2: attention softmax + dynamic kernel + bf16 pw ----
__global__ void k_prep(const float* __restrict__ pooled,
                       const float* __restrict__ attn_w,
                       const float* __restrict__ attn_b,
                       const float* __restrict__ bank,   // [4][128][1][3][3]
                       const float* __restrict__ pw_w,   // [128][128]
                       float* __restrict__ dynk,         // out: [8][128][9]
                       unsigned short* __restrict__ pwb) // out: [128][128] bf16
{
  __shared__ float attn_s[BB][KBANK];
  int tid = threadIdx.x;
  {
    // logits: 32 (b,k) pairs x 8 threads each
    int pr = tid >> 3, g = tid & 7;
    int b = pr >> 2, k = pr & 3;
    float s = 0.f;
    #pragma unroll
    for (int j = 0; j < 16; ++j) {
      int c = g * 16 + j;
      s += pooled[b * C_IN + c] * attn_w[k * C_IN + c];
    }
    s += __shfl_xor(s, 1);
    s += __shfl_xor(s, 2);
    s += __shfl_xor(s, 4);
    if (g == 0) attn_s[b][k] = s + attn_b[k];
  }
  __syncthreads();
  if (tid < BB) {
    int b = tid;
    float l0 = attn_s[b][0], l1 = attn_s[b][1], l2 = attn_s[b][2], l3 = attn_s[b][3];
    float m = fmaxf(fmaxf(l0, l1), fmaxf(l2, l3));
    float e0 = expf(l0 - m), e1 = expf(l1 - m), e2 = expf(l2 - m), e3 = expf(l3 - m);
    float inv = 1.0f / (e0 + e1 + e2 + e3);
    attn_s[b][0] = e0 * inv; attn_s[b][1] = e1 * inv;
    attn_s[b][2] = e2 * inv; attn_s[b][3] = e3 * inv;
  }
  __syncthreads();
  for (int i = tid; i < BB * C_IN * 9; i += 256) {
    int b = i / (C_IN * 9);
    int rem = i - b * (C_IN * 9);   // c*9 + ij
    float v = 0.f;
    #pragma unroll
    for (int k = 0; k < KBANK; ++k) v += attn_s[b][k] * bank[k * (C_IN * 9) + rem];
    dynk[i] = v;
  }
  for (int i = tid; i < OC_ * C_IN; i += 256) pwb[i] = f2bf(pw_w[i]);
}

// ---------------- Kernel 3: fused depthwise 3x3 + pointwise MFMA ----------
// Block: 256 threads (4 waves). Tile: b fixed, 8 rows x 16 cols = 128 px.
// GEMM per block: D[o=128][p=128] = sum_c pw[o][c]*dw[c][p], K chunked by 32.
__global__ __launch_bounds__(256, 3) void k_main(
    const float* __restrict__ x,
    const float* __restrict__ dynk,
    const unsigned short* __restrict__ pwb,
    const float* __restrict__ pw_b,
    float* __restrict__ out) {
  constexpr int RS = 18;           // xs row stride (dwords)
  constexpr int PS = 181;          // per-channel plane stride (ODD: bank spread)
  __shared__ float xs[32 * PS];             // 23168 B
  __shared__ unsigned short dws[128 * 40];  // [pixel][k_local pad40] 10240 B

  const int b  = blockIdx.z;
  const int h0 = blockIdx.y * 8;
  const int w0 = blockIdx.x * 16;
  const int tid  = threadIdx.x;
  const int wv   = tid >> 6;
  const int lane = tid & 63;
  const int quad = lane >> 4;
  const int l15  = lane & 15;
  const int cl   = tid & 31;  // depthwise: chunk-local channel
  const int prow = tid >> 5;  // depthwise: pixel row 0..7

  // ---- staging descriptors (computed once; chunk loop just bumps pointers)
  // primary segment: (c0 = tid>>3, r0 = tid&7); secondary (tid<64): r = 8,9
  const int c0 = tid >> 3, r0 = tid & 7;
  const int gh0 = h0 - 1 + r0;
  const bool ok0 = (unsigned)gh0 < 256u;
  const float* g0 = x + (((size_t)(b * C_IN + c0)) << 16)
                      + (size_t)(ok0 ? gh0 : 0) * 256 + (w0 - 1);
  float* s0p = xs + c0 * PS + r0 * RS;
  const int c1 = tid >> 1, r1 = 8 + (tid & 1);
  const int gh1 = h0 - 1 + r1;
  const bool ok1 = (unsigned)gh1 < 256u;
  const float* g1 = x + (((size_t)(b * C_IN + c1)) << 16)
                      + (size_t)(ok1 ? gh1 : 0) * 256 + (w0 - 1);
  float* s1p = xs + c1 * PS + r1 * RS;
  const bool has2 = tid < 64;
  const bool wL = (w0 > 0), wR = (w0 < 240);

  // A fragments (pw bf16) in registers for whole kernel.
  short8 afrag[2][4];
  #pragma unroll
  for (int mt = 0; mt < 2; ++mt)
    #pragma unroll
    for (int kc = 0; kc < 4; ++kc) {
      int o = wv * 32 + mt * 16 + l15;
      afrag[mt][kc] = *(const short8*)(pwb + ((size_t)o * C_IN + kc * 32 + quad * 8));
    }

  f32x4 acc[2][8];
  #pragma unroll
  for (int mt = 0; mt < 2; ++mt)
    #pragma unroll
    for (int nt = 0; nt < 8; ++nt)
      acc[mt][nt] = (f32x4){0.f, 0.f, 0.f, 0.f};

  #pragma unroll
  for (int kc = 0; kc < 4; ++kc) {
    __syncthreads();  // xs/dws consumers of chunk k-1 done
    // ---- stage x rows: all loads unconditional & aligned; edges via selects
    {
      float v[18];
      if (ok0) {
        float4 a = *(const float4*)(g0 + 1);
        float4 bq = *(const float4*)(g0 + 5);
        float4 cq = *(const float4*)(g0 + 9);
        float4 dq = *(const float4*)(g0 + 13);
        v[0] = wL ? g0[0] : 0.f;
        v[17] = wR ? g0[17] : 0.f;
        v[1] = a.x; v[2] = a.y; v[3] = a.z; v[4] = a.w;
        v[5] = bq.x; v[6] = bq.y; v[7] = bq.z; v[8] = bq.w;
        v[9] = cq.x; v[10] = cq.y; v[11] = cq.z; v[12] = cq.w;
        v[13] = dq.x; v[14] = dq.y; v[15] = dq.z; v[16] = dq.w;
      } else {
        #pragma unroll
        for (int j = 0; j < 18; ++j) v[j] = 0.f;
      }
      #pragma unroll
      for (int j = 0; j < 18; ++j) s0p[j] = v[j];
      if (has2) {
        float u[18];
        if (ok1) {
          float4 a = *(const float4*)(g1 + 1);
          float4 bq = *(const float4*)(g1 + 5);
          float4 cq = *(const float4*)(g1 + 9);
          float4 dq = *(const float4*)(g1 + 13);
          u[0] = wL ? g1[0] : 0.f;
          u[17] = wR ? g1[17] : 0.f;
          u[1] = a.x; u[2] = a.y; u[3] = a.z; u[4] = a.w;
          u[5] = bq.x; u[6] = bq.y; u[7] = bq.z; u[8] = bq.w;
          u[9] = cq.x; u[10] = cq.y; u[11] = cq.z; u[12] = cq.w;
          u[13] = dq.x; u[14] = dq.y; u[15] = dq.z; u[16] = dq.w;
        } else {
          #pragma unroll
          for (int j = 0; j < 18; ++j) u[j] = 0.f;
        }
        #pragma unroll
        for (int j = 0; j < 18; ++j) s1p[j] = u[j];
      }
      g0 += (size_t)32 << 16;
      g1 += (size_t)32 << 16;
    }
    __syncthreads();
    // ---- depthwise: thread = (channel cl, pixel row prow), 16 cols
    float k9[9];
    {
      const float* kp = dynk + (size_t)(b * C_IN + kc * 32 + cl) * 9;
      #pragma unroll
      for (int t = 0; t < 9; ++t) k9[t] = kp[t];
    }
    float accd[16];
    #pragma unroll
    for (int col = 0; col < 16; ++col) accd[col] = 0.f;
    const float* xp = &xs[cl * PS + prow * RS];
    #pragma unroll
    for (int i = 0; i < 3; ++i) {
      float xr[18];
      const float* rp = xp + i * RS;
      #pragma unroll
      for (int j = 0; j < 18; ++j) xr[j] = rp[j];
      float cc0 = k9[3 * i], cc1 = k9[3 * i + 1], cc2 = k9[3 * i + 2];
      #pragma unroll
      for (int col = 0; col < 16; ++col)
        accd[col] = fmaf(cc0, xr[col], fmaf(cc1, xr[col + 1], fmaf(cc2, xr[col + 2], accd[col])));
    }
    // dw -> LDS, MFMA-B layout: stored [pixel][k_local] stride 40
    #pragma unroll
    for (int col = 0; col < 16; ++col)
      dws[(prow * 16 + col) * 40 + cl] = f2bf(accd[col]);
    __syncthreads();
    // ---- MFMA: 16 per wave per chunk
    #pragma unroll
    for (int nt = 0; nt < 8; ++nt) {
      short8 bfrag = *(const short8*)&dws[(nt * 16 + l15) * 40 + quad * 8];
      acc[0][nt] = __builtin_amdgcn_mfma_f32_16x16x32_bf16(afrag[0][kc], bfrag, acc[0][nt], 0, 0, 0);
      acc[1][nt] = __builtin_amdgcn_mfma_f32_16x16x32_bf16(afrag[1][kc], bfrag, acc[1][nt], 0, 0, 0);
    }
  }
  // ---- epilogue: D[row=o][col=pixel]; pixel = nt*16 + l15 -> (h0+nt, w0+l15)
  #pragma unroll
  for (int mt = 0; mt < 2; ++mt) {
    #pragma unroll
    for (int r = 0; r < 4; ++r) {
      int o = wv * 32 + mt * 16 + quad * 4 + r;
      float bias = pw_b[o];
      size_t obase = ((size_t)(b * OC_ + o)) << 16;
      #pragma unroll
      for (int nt = 0; nt < 8; ++nt)
        out[obase + ((h0 + nt) << 8) + (w0 + l15)] = acc[mt][nt][r] + bias;
    }
  }
}

extern "C" void kernel_launch(void* const* d_in, const int* in_sizes, int n_in,
                              void* d_out, int out_size, void* d_ws, size_t ws_size,
                              hipStream_t stream) {
  const float* x      = (const float*)d_in[0];
  const float* bank   = (const float*)d_in[1];
  const float* attn_w = (const float*)d_in[2];
  const float* attn_b = (const float*)d_in[3];
  const float* pw_w   = (const float*)d_in[4];
  const float* pw_b   = (const float*)d_in[5];
  float* out = (float*)d_out;

  char* ws = (char*)d_ws;
  float* pooled       = (float*)ws;                       // 1024 f32
  float* dynk         = (float*)(ws + 4096);              // 9216 f32
  unsigned short* pwb = (unsigned short*)(ws + 4096 + 36864); // 16384 bf16

  k_pool<<<1024, 256, 0, stream>>>(x, pooled);
  k_prep<<<1, 256, 0, stream>>>(pooled, attn_w, attn_b, bank, pw_w, dynk, pwb);
  dim3 grid(16, 32, 8);  // (W/16, H/8, B)
  k_main<<<grid, 256, 0, stream>>>(x, dynk, pwb, pw_b, out);
}